// Round 5
// baseline (466.419 us; speedup 1.0000x reference)
//
#include <hip/hip_runtime.h>
#include <hip/hip_bf16.h>
#include <stdint.h>

// ---------------------------------------------------------------------------
// Pipeline:
//  K0 f32_to_bf16:    ws.Wnet_bf = bf16(W_net)                 [25088,1568]
//  K1 gemm_nt_lp:     ws.x_bf[:, :784] = bf16((xd@W_lp^T + b_lp - .5)/.2)
//  K2 build_restored: ws.x_bf[:, 784:] = bf16((x_restored - .5)/.2)
//  K3 gemm_mfma_256:  d_out = (x_bf @ Wnet_bf^T + b_net)*0.2   [2048,25088] f32
//                     256x256 tile, BK=32, 8 waves, 3-buffer LDS, fine
//                     2-phase interleave per K-tile (T3), counted vmcnt (T4),
//                     XOR-swizzled LDS (T2), setprio around MFMA (T5),
//                     XCD-banded blocks (T1).
//  K4a gram_solve:    per batch: G = W W^T (chunked MFMA), L = chol(G),
//                     M = diag(L) L^-1  -> ws (reuses Wnet_bf region)
//  K4b gs_apply:      out_i = w_i + sum_{j<i} M_ij w_j  (chunked, f32)
// ---------------------------------------------------------------------------

typedef short s16x8 __attribute__((ext_vector_type(8)));
typedef float f32x4 __attribute__((ext_vector_type(4)));

#define GL_LDS16(gptr, lptr)                                                   \
    __builtin_amdgcn_global_load_lds(                                          \
        (const __attribute__((address_space(1))) void*)(gptr),                 \
        (__attribute__((address_space(3))) void*)(lptr), 16, 0, 0)

// compiler-visible barrier that does NOT drain vmcnt (unlike __syncthreads)
#define PHASE_BARRIER()                                                        \
    do {                                                                       \
        asm volatile("" ::: "memory");                                         \
        __builtin_amdgcn_s_barrier();                                          \
        asm volatile("" ::: "memory");                                         \
        __builtin_amdgcn_sched_barrier(0);                                     \
    } while (0)

// ========================= K3: 256x256 MFMA GEMM ===========================
// C[m][n] = (sum_k A[m][k]*B[n][k] + bias[n]) * 0.2
// A: [M][K] bf16 row-major, B: [N][K] bf16 row-major. M%256==0, N%256==0,
// K%32==0. 512 threads = 8 waves (2 M-halves x 4 N-quarters); per-wave
// output 128x64 (8x4 16x16 frags).
//
// Schedule per K-tile (BK=32), 2 phases:
//   [tile start] s_waitcnt vmcnt(4)  (tile kt's 4 loads done; kt+1's stay
//                in flight) ; s_barrier
//   phase 0: ds_read B frags (4xb128) + A frags mi0-3 (4xb128);
//            stage A of tile kt+2; barrier; setprio1; 16 MFMA; setprio0;
//            barrier
//   phase 1: ds_read A frags mi4-7; stage B of tile kt+2; barrier;
//            setprio1; 16 MFMA; setprio0   (trailing barrier = next tile's)
// Buffers: 3 x 32KB; stage target (kt+2)%3 was last read at tile kt-1.
//
// LDS tile layout (per buffer half, [256 rows][32 bf16] = 64 B/row):
//   phys_byte = lin_byte ^ ((row & 6) << 3)   -> 0 bank conflicts (verified
//   round 4: SQ_LDS_BANK_CONFLICT 14.7M -> 0). global_load_lds writes
//   linearly, so the SOURCE global address is pre-swizzled; ds_read_b128
//   applies the same XOR (folds to a per-lane constant).
__global__ __launch_bounds__(512, 1) void gemm_mfma_256(
    const __hip_bfloat16* __restrict__ A, const __hip_bfloat16* __restrict__ B,
    const float* __restrict__ bias, float* __restrict__ C,
    int M, int N, int K)
{
    __shared__ __align__(16) short lds[3][16384];   // 96 KB

    const int t = threadIdx.x;
    const int l = t & 63;
    const int wv = t >> 6;          // wave 0..7
    const int wm = wv >> 2;         // M-half 0..1
    const int wn = wv & 3;          // N-quarter 0..3

    // XCD-banded mapping: XCD (f&7) owns output row-band yb, sweeps all xb.
    const int f  = blockIdx.x;      // grid = 784 = 8 * 98
    const int xb = f >> 3;
    const int yb = f & 7;
    const int m0 = yb * 256;
    const int n0 = xb * 256;

    const short* As = (const short*)A;
    const short* Bs = (const short*)B;

    // ---- staging source (per-lane, pre-swizzled; see round-4 notes) ----
    const int colE = ((((l & 3) << 4) ^ ((l & 24) << 1)) >> 1);
    const size_t baseA0 = (size_t)(m0 + wv * 32 +  0 + (l >> 2)) * K + colE;
    const size_t baseA1 = (size_t)(m0 + wv * 32 + 16 + (l >> 2)) * K + colE;
    const size_t baseB0 = (size_t)(n0 + wv * 32 +  0 + (l >> 2)) * K + colE;
    const size_t baseB1 = (size_t)(n0 + wv * 32 + 16 + (l >> 2)) * K + colE;
    const int dst0 = (wv * 2 + 0) * 512;    // LDS dest (shorts)
    const int dst1 = (wv * 2 + 1) * 512;

    // ---- fragment read offsets (shorts); XOR folds to per-lane constant ----
    const int xk   = ((l >> 4) * 16) ^ ((l & 6) << 3);           // bytes
    const int aoff = ((wm * 128 + (l & 15)) * 64 + xk) >> 1;
    const int boff = ((wn * 64  + (l & 15)) * 64 + xk) >> 1;

    f32x4 acc[8][4] = {};

#define STAGE_A(buf, T)                                                        \
    do {                                                                       \
        short* bA_ = &lds[buf][0];                                             \
        const size_t ko_ = (size_t)(T) * 32;                                   \
        GL_LDS16(As + baseA0 + ko_, bA_ + dst0);                               \
        GL_LDS16(As + baseA1 + ko_, bA_ + dst1);                               \
    } while (0)
#define STAGE_B(buf, T)                                                        \
    do {                                                                       \
        short* bB_ = &lds[buf][8192];                                          \
        const size_t ko_ = (size_t)(T) * 32;                                   \
        GL_LDS16(Bs + baseB0 + ko_, bB_ + dst0);                               \
        GL_LDS16(Bs + baseB1 + ko_, bB_ + dst1);                               \
    } while (0)

    const int NT = K >> 5;          // 49
    STAGE_A(0, 0); STAGE_B(0, 0);
    STAGE_A(1, 1); STAGE_B(1, 1);

    int cur = 0;
    for (int kt = 0; kt < NT; ++kt) {
        // tile kt ready; tile kt+1's 4 loads stay in flight (T4)
        if (kt < NT - 1) asm volatile("s_waitcnt vmcnt(4)");
        else             asm volatile("s_waitcnt vmcnt(0)");
        __builtin_amdgcn_sched_barrier(0);
        PHASE_BARRIER();

        int nb = cur + 2; if (nb >= 3) nb -= 3;
        const short* bA = &lds[cur][0];
        const short* bB = &lds[cur][8192];

        // ---------------- phase 0: B frags + A mi0-3 ----------------
        s16x8 bf[4], af[4];
        #pragma unroll
        for (int ni = 0; ni < 4; ++ni)
            bf[ni] = *(const s16x8*)&bB[boff + ni * 512];
        #pragma unroll
        for (int mi = 0; mi < 4; ++mi)
            af[mi] = *(const s16x8*)&bA[aoff + mi * 512];
        if (kt + 2 < NT) STAGE_A(nb, kt + 2);

        PHASE_BARRIER();
        __builtin_amdgcn_s_setprio(1);
        #pragma unroll
        for (int mi = 0; mi < 4; ++mi)
            #pragma unroll
            for (int ni = 0; ni < 4; ++ni)
                acc[mi][ni] = __builtin_amdgcn_mfma_f32_16x16x32_bf16(
                    af[mi], bf[ni], acc[mi][ni], 0, 0, 0);
        __builtin_amdgcn_s_setprio(0);
        PHASE_BARRIER();

        // ---------------- phase 1: A mi4-7 ----------------
        s16x8 ag[4];
        #pragma unroll
        for (int mi = 0; mi < 4; ++mi)
            ag[mi] = *(const s16x8*)&bA[aoff + (mi + 4) * 512];
        if (kt + 2 < NT) STAGE_B(nb, kt + 2);

        PHASE_BARRIER();
        __builtin_amdgcn_s_setprio(1);
        #pragma unroll
        for (int mi = 0; mi < 4; ++mi)
            #pragma unroll
            for (int ni = 0; ni < 4; ++ni)
                acc[mi + 4][ni] = __builtin_amdgcn_mfma_f32_16x16x32_bf16(
                    ag[mi], bf[ni], acc[mi + 4][ni], 0, 0, 0);
        __builtin_amdgcn_s_setprio(0);
        // trailing barrier is the next K-tile's start barrier

        ++cur; if (cur >= 3) cur = 0;
    }
#undef STAGE_A
#undef STAGE_B

    // ---- epilogue: C/D layout col = lane&15, row = (lane>>4)*4 + reg ----
    const int row0 = m0 + wm * 128 + ((l >> 4) << 2);
    const int col0 = n0 + wn * 64 + (l & 15);
    #pragma unroll
    for (int ni = 0; ni < 4; ++ni) {
        const int n = col0 + ni * 16;
        const float bn = bias[n];
        #pragma unroll
        for (int mi = 0; mi < 8; ++mi) {
            const int r0 = row0 + mi * 16;
            #pragma unroll
            for (int r = 0; r < 4; ++r)
                C[(size_t)(r0 + r) * N + n] = (acc[mi][ni][r] + bn) * 0.2f;
        }
    }
}

// ============================ K0: f32 -> bf16 ==============================
__global__ __launch_bounds__(256) void f32_to_bf16(
    const float* __restrict__ in, __hip_bfloat16* __restrict__ out, int n4)
{
    int i = blockIdx.x * blockDim.x + threadIdx.x;
    const int stride = gridDim.x * blockDim.x;
    for (; i < n4; i += stride) {
        float4 v = ((const float4*)in)[i];
        __hip_bfloat16 o[4] = {
            __float2bfloat16(v.x), __float2bfloat16(v.y),
            __float2bfloat16(v.z), __float2bfloat16(v.w)};
        *(ushort4*)&out[(size_t)i * 4] = *(const ushort4*)o;
    }
}

// ===================== K1: small fp32 GEMM (NT) ============================
#define TILE_M 64
#define TILE_N 64
#define TILE_K 16
#define LDS_STRIDE 72

__global__ __launch_bounds__(256) void gemm_nt_lp(
    const float* __restrict__ A, const float* __restrict__ B,
    const float* __restrict__ bias, __hip_bfloat16* __restrict__ C,
    int M, int N, int K, int ldc)
{
    __shared__ float As[TILE_K][LDS_STRIDE];
    __shared__ float Bsh[TILE_K][LDS_STRIDE];

    const int t  = threadIdx.x;
    const int tx = t & 15;
    const int ty = t >> 4;
    const int m0 = blockIdx.y * TILE_M;
    const int n0 = blockIdx.x * TILE_N;
    const int lrow = t >> 2;
    const int lk   = (t & 3) << 2;

    float acc[4][4] = {};

    for (int kt = 0; kt < K; kt += TILE_K) {
        float4 av = *(const float4*)(A + (size_t)(m0 + lrow) * K + kt + lk);
        float4 bv = make_float4(0.f, 0.f, 0.f, 0.f);
        if (n0 + lrow < N)
            bv = *(const float4*)(B + (size_t)(n0 + lrow) * K + kt + lk);

        __syncthreads();
        As[lk + 0][lrow] = av.x; As[lk + 1][lrow] = av.y;
        As[lk + 2][lrow] = av.z; As[lk + 3][lrow] = av.w;
        Bsh[lk + 0][lrow] = bv.x; Bsh[lk + 1][lrow] = bv.y;
        Bsh[lk + 2][lrow] = bv.z; Bsh[lk + 3][lrow] = bv.w;
        __syncthreads();

        #pragma unroll
        for (int k = 0; k < TILE_K; ++k) {
            float4 a = *(const float4*)&As[k][ty << 2];
            float4 b = *(const float4*)&Bsh[k][tx << 2];
            acc[0][0] += a.x * b.x; acc[0][1] += a.x * b.y;
            acc[0][2] += a.x * b.z; acc[0][3] += a.x * b.w;
            acc[1][0] += a.y * b.x; acc[1][1] += a.y * b.y;
            acc[1][2] += a.y * b.z; acc[1][3] += a.y * b.w;
            acc[2][0] += a.z * b.x; acc[2][1] += a.z * b.y;
            acc[2][2] += a.z * b.z; acc[2][3] += a.z * b.w;
            acc[3][0] += a.w * b.x; acc[3][1] += a.w * b.y;
            acc[3][2] += a.w * b.z; acc[3][3] += a.w * b.w;
        }
    }

    #pragma unroll
    for (int j = 0; j < 4; ++j) {
        int n = n0 + (tx << 2) + j;
        if (n < N) {
            float bn = bias[n];
            #pragma unroll
            for (int i = 0; i < 4; ++i) {
                float v = (acc[i][j] + bn - 0.5f) / 0.2f;
                C[(size_t)(m0 + (ty << 2) + i) * ldc + n] = __float2bfloat16(v);
            }
        }
    }
}

// ===================== K2: restored half, bf16 =============================
__global__ __launch_bounds__(256) void build_restored(
    const float* __restrict__ xr, __hip_bfloat16* __restrict__ x)
{
    const int b = blockIdx.x;
    const int t = threadIdx.x;
    if (t < 196) {
        float4 v = *(const float4*)(xr + (size_t)b * 784 + (t << 2));
        __hip_bfloat16 o[4] = {
            __float2bfloat16((v.x - 0.5f) / 0.2f),
            __float2bfloat16((v.y - 0.5f) / 0.2f),
            __float2bfloat16((v.z - 0.5f) / 0.2f),
            __float2bfloat16((v.w - 0.5f) / 0.2f)};
        *(ushort4*)&x[(size_t)b * 1568 + 784 + (t << 2)] = *(const ushort4*)o;
    }
}

// ==================== K4a: Gram + Cholesky solve ===========================
#define GS_N 32
#define GS_D 784

__global__ __launch_bounds__(256, 4) void gram_solve(
    const float* __restrict__ out, float* __restrict__ Mws)
{
    __shared__ __align__(16) short Wc[GS_N * 64];   // 4 KB, XOR-swizzled
    __shared__ float Gs[GS_N][GS_N + 1];            // 4224 B (G -> L)
    __shared__ float Ms[GS_N][GS_N + 1];            // 4224 B
    __shared__ float Ld[GS_N];

    const int t = threadIdx.x;
    const int l = t & 63;
    const int w = t >> 6;
    const float* row0 = out + (size_t)blockIdx.x * (GS_N * GS_D);

    const int wr = w >> 1, wc2 = w & 1;
    const int ra = wr * 16 + (l & 15);
    const int rb = wc2 * 16 + (l & 15);
    const int kg = l >> 4;

    f32x4 acc = {};

    for (int k0 = 0; k0 < 832; k0 += 64) {   // 13 chunks, k >= 784 zero-pad
        #pragma unroll
        for (int hh = 0; hh < 2; ++hh) {
            const int h   = t + hh * 256;    // 0..511 = 32 rows x 16 qgrans
            const int r   = h >> 4;
            const int hg  = h & 15;          // quarter-granule (4 elems)
            const int col = k0 + (hg << 2);
            ushort4 u = make_ushort4(0, 0, 0, 0);
            if (col < GS_D) {
                float4 v = *(const float4*)(row0 + r * GS_D + col);
                __hip_bfloat16 hb[4] = {
                    __float2bfloat16(v.x), __float2bfloat16(v.y),
                    __float2bfloat16(v.z), __float2bfloat16(v.w)};
                u = *(const ushort4*)hb;
            }
            const int gp = (hg >> 1) ^ (r & 7);   // 16B-granule swizzle
            *(ushort4*)&Wc[(r << 6) + (gp << 3) + ((hg & 1) << 2)] = u;
        }
        __syncthreads();

        #pragma unroll
        for (int s = 0; s < 2; ++s) {
            const int ga = ((s << 2) + kg) ^ (ra & 7);
            const int gb = ((s << 2) + kg) ^ (rb & 7);
            s16x8 af = *(const s16x8*)&Wc[(ra << 6) + (ga << 3)];
            s16x8 bf = *(const s16x8*)&Wc[(rb << 6) + (gb << 3)];
            acc = __builtin_amdgcn_mfma_f32_16x16x32_bf16(af, bf, acc, 0, 0, 0);
        }
        __syncthreads();
    }

    {
        const int di = wr * 16 + (l >> 4) * 4;
        const int dj = wc2 * 16 + (l & 15);
        #pragma unroll
        for (int r = 0; r < 4; ++r) Gs[di + r][dj] = acc[r];
    }
    for (int z = t; z < GS_N * (GS_N + 1); z += 256) ((float*)Ms)[z] = 0.f;
    __syncthreads();

    // Cholesky, lower triangle in place (diag in Ld)
    for (int k = 0; k < GS_N; ++k) {
        const float sk = sqrtf(Gs[k][k]);
        if (t == k) Ld[k] = sk;
        if (t > k && t < GS_N) Gs[t][k] /= sk;
        __syncthreads();
        if (t > k && t < GS_N) {
            const float lik = Gs[t][k];
            for (int j = k + 1; j <= t; ++j)
                Gs[t][j] -= lik * Gs[j][k];
        }
        __syncthreads();
    }

    // M = diag(L) * L^-1, column-parallel forward substitution
    if (t < GS_N) {
        const int j = t;
        Ms[j][j] = 1.0f / Ld[j];
        for (int i = j + 1; i < GS_N; ++i) {
            float a = 0.f;
            for (int k = j; k < i; ++k)
                a += Gs[i][k] * Ms[k][j];
            Ms[i][j] = -a / Ld[i];
        }
        for (int i = j + 1; i < GS_N; ++i)
            Ms[i][j] *= Ld[i];
    }
    __syncthreads();

    {
        const int i = t >> 3, j0 = (t & 7) << 2;
        float4 mv = make_float4(Ms[i][j0], Ms[i][j0 + 1],
                                Ms[i][j0 + 2], Ms[i][j0 + 3]);
        *(float4*)(Mws + (size_t)blockIdx.x * 1024 + (t << 2)) = mv;
    }
}

// ======================= K4b: apply correction =============================
__global__ __launch_bounds__(256, 8) void gs_apply(
    float* __restrict__ out, const float* __restrict__ Mws)
{
    __shared__ float4 Wf[GS_N][28];     // 14336 B (f32 chunk)
    __shared__ float  Ml[GS_N][36];     // 4608 B (padded for f4 writes)

    const int t = threadIdx.x;
    const int b = blockIdx.y;
    const int k0 = blockIdx.x * 112;
    float* row0 = out + (size_t)b * (GS_N * GS_D);

    {
        float4 mv = *(const float4*)(Mws + (size_t)b * 1024 + (t << 2));
        const int i = t >> 3, j0 = (t & 7) << 2;
        *(float4*)&Ml[i][j0] = mv;
    }
    #pragma unroll
    for (int hh = 0; hh < 4; ++hh) {
        const int h = t + hh * 256;     // 0..1023
        const int r = h >> 5, c = h & 31;
        if (c < 28)
            Wf[r][c] = *(const float4*)(row0 + r * GS_D + k0 + (c << 2));
    }
    __syncthreads();

    const int rg = t >> 5;              // row group: rows rg*4 .. rg*4+3
    const int c4 = t & 31;              // float4 column
    if (c4 < 28) {
        const int i0 = rg << 2;
        float4 c0 = Wf[i0 + 0][c4];
        float4 c1 = Wf[i0 + 1][c4];
        float4 c2 = Wf[i0 + 2][c4];
        float4 c3 = Wf[i0 + 3][c4];
        for (int j = 0; j < GS_N - 1; ++j) {
            if (j > i0 + 2) break;
            const float4 wj = Wf[j][c4];
            const float m0 = (i0 + 0 > j) ? Ml[i0 + 0][j] : 0.f;
            const float m1 = (i0 + 1 > j) ? Ml[i0 + 1][j] : 0.f;
            const float m2 = (i0 + 2 > j) ? Ml[i0 + 2][j] : 0.f;
            const float m3 = (i0 + 3 > j) ? Ml[i0 + 3][j] : 0.f;
            c0.x += m0 * wj.x; c0.y += m0 * wj.y;
            c0.z += m0 * wj.z; c0.w += m0 * wj.w;
            c1.x += m1 * wj.x; c1.y += m1 * wj.y;
            c1.z += m1 * wj.z; c1.w += m1 * wj.w;
            c2.x += m2 * wj.x; c2.y += m2 * wj.y;
            c2.z += m2 * wj.z; c2.w += m2 * wj.w;
            c3.x += m3 * wj.x; c3.y += m3 * wj.y;
            c3.z += m3 * wj.z; c3.w += m3 * wj.w;
        }
        *(float4*)(row0 + (i0 + 0) * GS_D + k0 + (c4 << 2)) = c0;
        *(float4*)(row0 + (i0 + 1) * GS_D + k0 + (c4 << 2)) = c1;
        *(float4*)(row0 + (i0 + 2) * GS_D + k0 + (c4 << 2)) = c2;
        *(float4*)(row0 + (i0 + 3) * GS_D + k0 + (c4 << 2)) = c3;
    }
}

// ================================ launch ===================================
extern "C" void kernel_launch(void* const* d_in, const int* in_sizes, int n_in,
                              void* d_out, int out_size, void* d_ws, size_t ws_size,
                              hipStream_t stream)
{
    const float* xd   = (const float*)d_in[0];  // [2048, 832]
    const float* xr   = (const float*)d_in[1];  // [2048, 1, 28, 28]
    const float* Wlp  = (const float*)d_in[2];  // [784, 832]
    const float* blp  = (const float*)d_in[3];  // [784]
    const float* Wnet = (const float*)d_in[4];  // [25088, 1568]
    const float* bnet = (const float*)d_in[5];  // [25088]
    float* out = (float*)d_out;                 // [2048, 32, 784] f32

    const int B = 2048, IN_LP = 832, IMG = 784, IN_NET = 1568, OUT = 32 * 784;

    __hip_bfloat16* Wnet_bf = (__hip_bfloat16*)d_ws;
    __hip_bfloat16* x_bf =
        (__hip_bfloat16*)((char*)d_ws + (size_t)OUT * IN_NET * 2);
    // M workspace overlays Wnet_bf region (free after K3; stream-ordered).
    float* Mws = (float*)d_ws;                  // [2048][32][32] f32 = 8.4 MB

    // K0: W_net fp32 -> bf16
    f32_to_bf16<<<2048, 256, 0, stream>>>(Wnet, Wnet_bf, OUT * IN_NET / 4);

    // K1: linear projection + normalize -> bf16 x[:, :784]
    gemm_nt_lp<<<dim3((IMG + TILE_N - 1) / TILE_N, B / TILE_M), 256, 0, stream>>>(
        xd, Wlp, blp, x_bf, B, IMG, IN_LP, IN_NET);

    // K2: normalized restored image -> bf16 x[:, 784:]
    build_restored<<<B, 256, 0, stream>>>(xr, x_bf);

    // K3: big MFMA GEMM -> d_out (fp32); grid 784 = 8 XCD bands x 98
    gemm_mfma_256<<<dim3(784), 512, 0, stream>>>(
        x_bf, Wnet_bf, bnet, out, B, OUT, IN_NET);

    // K4a: per-batch Gram + Cholesky -> M
    gram_solve<<<B, 256, 0, stream>>>(out, Mws);

    // K4b: apply rank-32 correction in place
    gs_apply<<<dim3(7, B), 256, 0, stream>>>(out, Mws);
}

// Round 6
// 455.708 us; speedup vs baseline: 1.0235x; 1.0235x over previous
//
#include <hip/hip_runtime.h>
#include <hip/hip_bf16.h>
#include <stdint.h>

// ---------------------------------------------------------------------------
// Pipeline (K padded 1568 -> 1600 so BK=64 divides; pad cols are zeros):
//  K0 wnet_to_bf16:   ws.Wnet_bf[r][0:1568] = bf16(W_net[r]); [1568:1600]=0
//  K1 gemm_nt_lp:     ws.x_bf[:, :784] = bf16((xd@W_lp^T + b_lp - .5)/.2)
//  K2 build_restored: ws.x_bf[:, 784:1568] = bf16((xr - .5)/.2); pad = 0
//  K3 gemm_mfma_256:  d_out = (x_bf @ Wnet_bf^T + b_net)*0.2   [2048,25088] f32
//                     256x256 tile, BK=64, 8 waves, 2-buffer LDS (128 KB),
//                     ONE __syncthreads + ONE vmcnt drain per K64-tile
//                     (stage->use distance = full tile >> HBM latency),
//                     XOR-swizzled LDS, XCD-banded blocks.
//  K4a gram_solve:    per batch: G = W W^T (chunked MFMA), L = chol(G),
//                     M = diag(L) L^-1  -> ws (reuses Wnet_bf region)
//  K4b gs_apply:      out_i = w_i + sum_{j<i} M_ij w_j  (chunked, f32)
// ---------------------------------------------------------------------------

typedef short s16x8 __attribute__((ext_vector_type(8)));
typedef float f32x4 __attribute__((ext_vector_type(4)));

#define GL_LDS16(gptr, lptr)                                                   \
    __builtin_amdgcn_global_load_lds(                                          \
        (const __attribute__((address_space(1))) void*)(gptr),                 \
        (__attribute__((address_space(3))) void*)(lptr), 16, 0, 0)

#define KP 1600   // padded K

// ========================= K3: 256x256 MFMA GEMM ===========================
// C[m][n] = (sum_k A[m][k]*B[n][k] + bias[n]) * 0.2
// A: [M][KP] bf16 row-major, B: [N][KP] bf16 row-major (pad cols zero).
// 512 threads = 8 waves (2 M-halves x 4 N-quarters); per-wave output 128x64.
//
// Per K64-tile, per wave: 8 stage gloads (issued at tile start, consumed a
// full tile later -> __syncthreads' vmcnt(0) drain is free), 24 ds_read_b128
// (8 B frags held all tile; A-half regs reused lo->hi), 64 MFMA, 1 barrier.
//
// LDS per buffer: A [2 halves][128 rows][64 bf16] 32 KB + B same 32 KB.
// Swizzle (short units): phys = lin ^ ((row & 7) << 3). Fragment read:
// 64 lanes hit bank-quad (kg ^ (l&7)) -> uniform 8 words/bank (minimal).
// global_load_lds writes linearly; source col pre-swizzled:
//   colE = ((l&7) ^ (l>>3)) * 8, row_in_half = wv*8 + (l>>3) + j*64.
__global__ __launch_bounds__(512, 1) void gemm_mfma_256(
    const __hip_bfloat16* __restrict__ A, const __hip_bfloat16* __restrict__ B,
    const float* __restrict__ bias, float* __restrict__ C,
    int M, int N, int K)
{
    __shared__ __align__(16) short lds[2][32768];   // 128 KB

    const int t = threadIdx.x;
    const int l = t & 63;
    const int wv = t >> 6;          // wave 0..7
    const int wm = wv >> 2;         // M-half 0..1
    const int wn = wv & 3;          // N-quarter 0..3

    // XCD-banded mapping: XCD (f&7) owns output row-band yb, sweeps all xb.
    const int f  = blockIdx.x;      // grid = 784 = 8 * 98
    const int xb = f >> 3;
    const int yb = f & 7;
    const int m0 = yb * 256;
    const int n0 = xb * 256;

    const short* As = (const short*)A;
    const short* Bs = (const short*)B;

    // ---- staging source bases (element units, per-lane, pre-swizzled) ----
    const int colE = (((l & 7) ^ (l >> 3)) << 3);
    const size_t aSrc0 = (size_t)(m0 +   0 + wv * 8 + (l >> 3)) * KP + colE;
    const size_t aSrc1 = (size_t)(m0 + 128 + wv * 8 + (l >> 3)) * KP + colE;
    const size_t bSrc0 = (size_t)(n0 +   0 + wv * 8 + (l >> 3)) * KP + colE;
    const size_t bSrc1 = (size_t)(n0 + 128 + wv * 8 + (l >> 3)) * KP + colE;
    const int dstW = wv * 512;      // per-wave LDS dest offset (shorts)

    // ---- fragment read constants (short units) ----
    // in-half row = (frag base mult of 16) + (l&15); row&7 = l&7.
    const int sk0 = (((l >> 4) << 3)) ^ ((l & 7) << 3);  // ks=0 swizzled col
    const int sk1 = sk0 ^ 32;                             // ks=1
    const int aBase = wm * 8192 + (l & 15) * 64;                  // A region
    const int bBase = 16384 + (wn >> 1) * 8192 +
                      ((wn & 1) * 64 + (l & 15)) * 64;            // B region

    f32x4 acc[8][4] = {};

#define STAGE_TILE(buf, T)                                                     \
    do {                                                                       \
        short* d_ = &lds[buf][0];                                              \
        const size_t ko_ = (size_t)(T) * 64;                                   \
        GL_LDS16(As + aSrc0 + ko_,            d_ + dstW);                      \
        GL_LDS16(As + aSrc0 + 64 * KP + ko_,  d_ + dstW + 4096);               \
        GL_LDS16(As + aSrc1 + ko_,            d_ + dstW + 8192);               \
        GL_LDS16(As + aSrc1 + 64 * KP + ko_,  d_ + dstW + 12288);              \
        GL_LDS16(Bs + bSrc0 + ko_,            d_ + dstW + 16384);              \
        GL_LDS16(Bs + bSrc0 + 64 * KP + ko_,  d_ + dstW + 20480);              \
        GL_LDS16(Bs + bSrc1 + ko_,            d_ + dstW + 24576);              \
        GL_LDS16(Bs + bSrc1 + 64 * KP + ko_,  d_ + dstW + 28672);              \
    } while (0)

    const int NT = K >> 6;          // 25
    STAGE_TILE(0, 0);
    __syncthreads();                // drains vmcnt(0): tile 0 ready

    for (int kt = 0; kt < NT; ++kt) {
        const int cur = kt & 1;
        const short* bufc = &lds[cur][0];

        // stage tile kt+1 into the other buffer (its readers finished at the
        // __syncthreads ending tile kt-1; its loads drain at this tile's end)
        if (kt + 1 < NT) STAGE_TILE(cur ^ 1, kt + 1);

        // ---- B fragments: all 8, held for the whole tile ----
        s16x8 bfr[4][2];
        #pragma unroll
        for (int ni = 0; ni < 4; ++ni) {
            bfr[ni][0] = *(const s16x8*)&bufc[bBase + ni * 1024 + sk0];
            bfr[ni][1] = *(const s16x8*)&bufc[bBase + ni * 1024 + sk1];
        }

        // ---- A halves: lo (rows 0-63 of wave tile) then hi (64-127) ----
        #pragma unroll
        for (int half = 0; half < 2; ++half) {
            s16x8 afr[4][2];
            #pragma unroll
            for (int mi = 0; mi < 4; ++mi) {
                const int ro = (half * 64 + mi * 16) * 64;
                afr[mi][0] = *(const s16x8*)&bufc[aBase + ro + sk0];
                afr[mi][1] = *(const s16x8*)&bufc[aBase + ro + sk1];
            }
            __builtin_amdgcn_s_setprio(1);
            #pragma unroll
            for (int mi = 0; mi < 4; ++mi)
                #pragma unroll
                for (int ni = 0; ni < 4; ++ni) {
                    acc[half * 4 + mi][ni] =
                        __builtin_amdgcn_mfma_f32_16x16x32_bf16(
                            afr[mi][0], bfr[ni][0], acc[half * 4 + mi][ni],
                            0, 0, 0);
                    acc[half * 4 + mi][ni] =
                        __builtin_amdgcn_mfma_f32_16x16x32_bf16(
                            afr[mi][1], bfr[ni][1], acc[half * 4 + mi][ni],
                            0, 0, 0);
                }
            __builtin_amdgcn_s_setprio(0);
        }

        // one barrier per K64-tile; also drains vmcnt(0) for tile kt+1's
        // stages (issued ~a full tile ago -> latency fully covered)
        __syncthreads();
    }
#undef STAGE_TILE

    // ---- epilogue: C/D layout col = lane&15, row = (lane>>4)*4 + reg ----
    const int row0 = m0 + wm * 128 + ((l >> 4) << 2);
    const int col0 = n0 + wn * 64 + (l & 15);
    #pragma unroll
    for (int ni = 0; ni < 4; ++ni) {
        const int n = col0 + ni * 16;
        const float bn = bias[n];
        #pragma unroll
        for (int mi = 0; mi < 8; ++mi) {
            const int r0 = row0 + mi * 16;
            #pragma unroll
            for (int r = 0; r < 4; ++r)
                C[(size_t)(r0 + r) * N + n] = (acc[mi][ni][r] + bn) * 0.2f;
        }
    }
}

// ==================== K0: W_net f32 -> bf16 (padded) =======================
// One block per row: convert 1568 elems, zero cols 1568..1599.
__global__ __launch_bounds__(256) void wnet_to_bf16(
    const float* __restrict__ in, __hip_bfloat16* __restrict__ out)
{
    const size_t r = blockIdx.x;
    const int t = threadIdx.x;
    const float* src = in + r * 1568;
    __hip_bfloat16* dst = out + r * KP;

    for (int i = t; i < 392; i += 256) {        // 392 float4 = 1568
        float4 v = *(const float4*)(src + (i << 2));
        __hip_bfloat16 o[4] = {
            __float2bfloat16(v.x), __float2bfloat16(v.y),
            __float2bfloat16(v.z), __float2bfloat16(v.w)};
        *(ushort4*)&dst[i << 2] = *(const ushort4*)o;
    }
    if (t < 8)                                   // pad: 32 bf16 zeros
        *(ushort4*)&dst[1568 + (t << 2)] = make_ushort4(0, 0, 0, 0);
}

// ===================== K1: small fp32 GEMM (NT) ============================
#define TILE_M 64
#define TILE_N 64
#define TILE_K 16
#define LDS_STRIDE 72

__global__ __launch_bounds__(256) void gemm_nt_lp(
    const float* __restrict__ A, const float* __restrict__ B,
    const float* __restrict__ bias, __hip_bfloat16* __restrict__ C,
    int M, int N, int K, int ldc)
{
    __shared__ float As[TILE_K][LDS_STRIDE];
    __shared__ float Bsh[TILE_K][LDS_STRIDE];

    const int t  = threadIdx.x;
    const int tx = t & 15;
    const int ty = t >> 4;
    const int m0 = blockIdx.y * TILE_M;
    const int n0 = blockIdx.x * TILE_N;
    const int lrow = t >> 2;
    const int lk   = (t & 3) << 2;

    float acc[4][4] = {};

    for (int kt = 0; kt < K; kt += TILE_K) {
        float4 av = *(const float4*)(A + (size_t)(m0 + lrow) * K + kt + lk);
        float4 bv = make_float4(0.f, 0.f, 0.f, 0.f);
        if (n0 + lrow < N)
            bv = *(const float4*)(B + (size_t)(n0 + lrow) * K + kt + lk);

        __syncthreads();
        As[lk + 0][lrow] = av.x; As[lk + 1][lrow] = av.y;
        As[lk + 2][lrow] = av.z; As[lk + 3][lrow] = av.w;
        Bsh[lk + 0][lrow] = bv.x; Bsh[lk + 1][lrow] = bv.y;
        Bsh[lk + 2][lrow] = bv.z; Bsh[lk + 3][lrow] = bv.w;
        __syncthreads();

        #pragma unroll
        for (int k = 0; k < TILE_K; ++k) {
            float4 a = *(const float4*)&As[k][ty << 2];
            float4 b = *(const float4*)&Bsh[k][tx << 2];
            acc[0][0] += a.x * b.x; acc[0][1] += a.x * b.y;
            acc[0][2] += a.x * b.z; acc[0][3] += a.x * b.w;
            acc[1][0] += a.y * b.x; acc[1][1] += a.y * b.y;
            acc[1][2] += a.y * b.z; acc[1][3] += a.y * b.w;
            acc[2][0] += a.z * b.x; acc[2][1] += a.z * b.y;
            acc[2][2] += a.z * b.z; acc[2][3] += a.z * b.w;
            acc[3][0] += a.w * b.x; acc[3][1] += a.w * b.y;
            acc[3][2] += a.w * b.z; acc[3][3] += a.w * b.w;
        }
    }

    #pragma unroll
    for (int j = 0; j < 4; ++j) {
        int n = n0 + (tx << 2) + j;
        if (n < N) {
            float bn = bias[n];
            #pragma unroll
            for (int i = 0; i < 4; ++i) {
                float v = (acc[i][j] + bn - 0.5f) / 0.2f;
                C[(size_t)(m0 + (ty << 2) + i) * ldc + n] = __float2bfloat16(v);
            }
        }
    }
}

// ===================== K2: restored half, bf16 (padded) ====================
__global__ __launch_bounds__(256) void build_restored(
    const float* __restrict__ xr, __hip_bfloat16* __restrict__ x)
{
    const int b = blockIdx.x;
    const int t = threadIdx.x;
    if (t < 196) {
        float4 v = *(const float4*)(xr + (size_t)b * 784 + (t << 2));
        __hip_bfloat16 o[4] = {
            __float2bfloat16((v.x - 0.5f) / 0.2f),
            __float2bfloat16((v.y - 0.5f) / 0.2f),
            __float2bfloat16((v.z - 0.5f) / 0.2f),
            __float2bfloat16((v.w - 0.5f) / 0.2f)};
        *(ushort4*)&x[(size_t)b * KP + 784 + (t << 2)] = *(const ushort4*)o;
    } else if (t < 204) {                        // pad cols 1568..1599
        *(ushort4*)&x[(size_t)b * KP + 1568 + ((t - 196) << 2)] =
            make_ushort4(0, 0, 0, 0);
    }
}

// ==================== K4a: Gram + Cholesky solve ===========================
#define GS_N 32
#define GS_D 784

__global__ __launch_bounds__(256, 4) void gram_solve(
    const float* __restrict__ out, float* __restrict__ Mws)
{
    __shared__ __align__(16) short Wc[GS_N * 64];   // 4 KB, XOR-swizzled
    __shared__ float Gs[GS_N][GS_N + 1];            // 4224 B (G -> L)
    __shared__ float Ms[GS_N][GS_N + 1];            // 4224 B
    __shared__ float Ld[GS_N];

    const int t = threadIdx.x;
    const int l = t & 63;
    const int w = t >> 6;
    const float* row0 = out + (size_t)blockIdx.x * (GS_N * GS_D);

    const int wr = w >> 1, wc2 = w & 1;
    const int ra = wr * 16 + (l & 15);
    const int rb = wc2 * 16 + (l & 15);
    const int kg = l >> 4;

    f32x4 acc = {};

    for (int k0 = 0; k0 < 832; k0 += 64) {   // 13 chunks, k >= 784 zero-pad
        #pragma unroll
        for (int hh = 0; hh < 2; ++hh) {
            const int h   = t + hh * 256;    // 0..511 = 32 rows x 16 qgrans
            const int r   = h >> 4;
            const int hg  = h & 15;          // quarter-granule (4 elems)
            const int col = k0 + (hg << 2);
            ushort4 u = make_ushort4(0, 0, 0, 0);
            if (col < GS_D) {
                float4 v = *(const float4*)(row0 + r * GS_D + col);
                __hip_bfloat16 hb[4] = {
                    __float2bfloat16(v.x), __float2bfloat16(v.y),
                    __float2bfloat16(v.z), __float2bfloat16(v.w)};
                u = *(const ushort4*)hb;
            }
            const int gp = (hg >> 1) ^ (r & 7);   // 16B-granule swizzle
            *(ushort4*)&Wc[(r << 6) + (gp << 3) + ((hg & 1) << 2)] = u;
        }
        __syncthreads();

        #pragma unroll
        for (int s = 0; s < 2; ++s) {
            const int ga = ((s << 2) + kg) ^ (ra & 7);
            const int gb = ((s << 2) + kg) ^ (rb & 7);
            s16x8 af = *(const s16x8*)&Wc[(ra << 6) + (ga << 3)];
            s16x8 bf = *(const s16x8*)&Wc[(rb << 6) + (gb << 3)];
            acc = __builtin_amdgcn_mfma_f32_16x16x32_bf16(af, bf, acc, 0, 0, 0);
        }
        __syncthreads();
    }

    {
        const int di = wr * 16 + (l >> 4) * 4;
        const int dj = wc2 * 16 + (l & 15);
        #pragma unroll
        for (int r = 0; r < 4; ++r) Gs[di + r][dj] = acc[r];
    }
    for (int z = t; z < GS_N * (GS_N + 1); z += 256) ((float*)Ms)[z] = 0.f;
    __syncthreads();

    // Cholesky, lower triangle in place (diag in Ld)
    for (int k = 0; k < GS_N; ++k) {
        const float sk = sqrtf(Gs[k][k]);
        if (t == k) Ld[k] = sk;
        if (t > k && t < GS_N) Gs[t][k] /= sk;
        __syncthreads();
        if (t > k && t < GS_N) {
            const float lik = Gs[t][k];
            for (int j = k + 1; j <= t; ++j)
                Gs[t][j] -= lik * Gs[j][k];
        }
        __syncthreads();
    }

    // M = diag(L) * L^-1, column-parallel forward substitution
    if (t < GS_N) {
        const int j = t;
        Ms[j][j] = 1.0f / Ld[j];
        for (int i = j + 1; i < GS_N; ++i) {
            float a = 0.f;
            for (int k = j; k < i; ++k)
                a += Gs[i][k] * Ms[k][j];
            Ms[i][j] = -a / Ld[i];
        }
        for (int i = j + 1; i < GS_N; ++i)
            Ms[i][j] *= Ld[i];
    }
    __syncthreads();

    {
        const int i = t >> 3, j0 = (t & 7) << 2;
        float4 mv = make_float4(Ms[i][j0], Ms[i][j0 + 1],
                                Ms[i][j0 + 2], Ms[i][j0 + 3]);
        *(float4*)(Mws + (size_t)blockIdx.x * 1024 + (t << 2)) = mv;
    }
}

// ======================= K4b: apply correction =============================
__global__ __launch_bounds__(256, 8) void gs_apply(
    float* __restrict__ out, const float* __restrict__ Mws)
{
    __shared__ float4 Wf[GS_N][28];     // 14336 B (f32 chunk)
    __shared__ float  Ml[GS_N][36];     // 4608 B (padded for f4 writes)

    const int t = threadIdx.x;
    const int b = blockIdx.y;
    const int k0 = blockIdx.x * 112;
    float* row0 = out + (size_t)b * (GS_N * GS_D);

    {
        float4 mv = *(const float4*)(Mws + (size_t)b * 1024 + (t << 2));
        const int i = t >> 3, j0 = (t & 7) << 2;
        *(float4*)&Ml[i][j0] = mv;
    }
    #pragma unroll
    for (int hh = 0; hh < 4; ++hh) {
        const int h = t + hh * 256;     // 0..1023
        const int r = h >> 5, c = h & 31;
        if (c < 28)
            Wf[r][c] = *(const float4*)(row0 + r * GS_D + k0 + (c << 2));
    }
    __syncthreads();

    const int rg = t >> 5;              // row group: rows rg*4 .. rg*4+3
    const int c4 = t & 31;              // float4 column
    if (c4 < 28) {
        const int i0 = rg << 2;
        float4 c0 = Wf[i0 + 0][c4];
        float4 c1 = Wf[i0 + 1][c4];
        float4 c2 = Wf[i0 + 2][c4];
        float4 c3 = Wf[i0 + 3][c4];
        for (int j = 0; j < GS_N - 1; ++j) {
            if (j > i0 + 2) break;
            const float4 wj = Wf[j][c4];
            const float m0 = (i0 + 0 > j) ? Ml[i0 + 0][j] : 0.f;
            const float m1 = (i0 + 1 > j) ? Ml[i0 + 1][j] : 0.f;
            const float m2 = (i0 + 2 > j) ? Ml[i0 + 2][j] : 0.f;
            const float m3 = (i0 + 3 > j) ? Ml[i0 + 3][j] : 0.f;
            c0.x += m0 * wj.x; c0.y += m0 * wj.y;
            c0.z += m0 * wj.z; c0.w += m0 * wj.w;
            c1.x += m1 * wj.x; c1.y += m1 * wj.y;
            c1.z += m1 * wj.z; c1.w += m1 * wj.w;
            c2.x += m2 * wj.x; c2.y += m2 * wj.y;
            c2.z += m2 * wj.z; c2.w += m2 * wj.w;
            c3.x += m3 * wj.x; c3.y += m3 * wj.y;
            c3.z += m3 * wj.z; c3.w += m3 * wj.w;
        }
        *(float4*)(row0 + (i0 + 0) * GS_D + k0 + (c4 << 2)) = c0;
        *(float4*)(row0 + (i0 + 1) * GS_D + k0 + (c4 << 2)) = c1;
        *(float4*)(row0 + (i0 + 2) * GS_D + k0 + (c4 << 2)) = c2;
        *(float4*)(row0 + (i0 + 3) * GS_D + k0 + (c4 << 2)) = c3;
    }
}

// ================================ launch ===================================
extern "C" void kernel_launch(void* const* d_in, const int* in_sizes, int n_in,
                              void* d_out, int out_size, void* d_ws, size_t ws_size,
                              hipStream_t stream)
{
    const float* xd   = (const float*)d_in[0];  // [2048, 832]
    const float* xr   = (const float*)d_in[1];  // [2048, 1, 28, 28]
    const float* Wlp  = (const float*)d_in[2];  // [784, 832]
    const float* blp  = (const float*)d_in[3];  // [784]
    const float* Wnet = (const float*)d_in[4];  // [25088, 1568]
    const float* bnet = (const float*)d_in[5];  // [25088]
    float* out = (float*)d_out;                 // [2048, 32, 784] f32

    const int B = 2048, IN_LP = 832, IMG = 784, OUT = 32 * 784;

    // workspace: [Wnet_bf: 25088*1600*2 = 80.28 MB][x_bf: 2048*1600*2 = 6.55 MB]
    __hip_bfloat16* Wnet_bf = (__hip_bfloat16*)d_ws;
    __hip_bfloat16* x_bf =
        (__hip_bfloat16*)((char*)d_ws + (size_t)OUT * KP * 2);
    // M workspace overlays Wnet_bf region (free after K3; stream-ordered).
    float* Mws = (float*)d_ws;                  // [2048][32][32] f32 = 8.4 MB

    // K0: W_net fp32 -> bf16, padded to KP
    wnet_to_bf16<<<OUT, 256, 0, stream>>>(Wnet, Wnet_bf);

    // K1: linear projection + normalize -> bf16 x[:, :784] (ld = KP)
    gemm_nt_lp<<<dim3((IMG + TILE_N - 1) / TILE_N, B / TILE_M), 256, 0, stream>>>(
        xd, Wlp, blp, x_bf, B, IMG, IN_LP, KP);

    // K2: normalized restored image -> bf16 x[:, 784:1568]; pad zeros
    build_restored<<<B, 256, 0, stream>>>(xr, x_bf);

    // K3: big MFMA GEMM -> d_out (fp32); grid 784 = 8 XCD bands x 98
    gemm_mfma_256<<<dim3(784), 512, 0, stream>>>(
        x_bf, Wnet_bf, bnet, out, B, OUT, KP);

    // K4a: per-batch Gram + Cholesky -> M
    gram_solve<<<B, 256, 0, stream>>>(out, Mws);

    // K4b: apply rank-32 correction in place
    gs_apply<<<dim3(7, B), 256, 0, stream>>>(out, Mws);
}

// Round 7
// 448.144 us; speedup vs baseline: 1.0408x; 1.0169x over previous
//
#include <hip/hip_runtime.h>
#include <hip/hip_bf16.h>
#include <stdint.h>

// ---------------------------------------------------------------------------
// Pipeline (K padded 1568 -> 1600 so BK=64 divides; pad cols are zeros):
//  K0 wnet_to_bf16:   ws.Wnet_bf[r][0:1568] = bf16(W_net[r]); [1568:1600]=0
//  K1 gemm_nt_lp:     ws.x_bf[:, :784] = bf16((xd@W_lp^T + b_lp - .5)/.2)
//  K2 build_restored: ws.x_bf[:, 784:1568] = bf16((xr - .5)/.2); pad = 0
//  K3 gemm_mfma_256:  d_out = (x_bf @ Wnet_bf^T + b_net)*0.2   [2048,25088] f32
//                     256x224 tile (grid 896 = 3.5*256 -> 87.5% tail vs
//                     784's 76.6%), BK=64, 8 waves (4M x 2N), 2-buffer LDS
//                     (120 KB), ONE __syncthreads + vmcnt drain per K64-tile,
//                     XOR-swizzled LDS (0 conflicts, verified r4), XCD bands.
//  K4a gram_solve:    per batch: G = W W^T (chunked MFMA), L = chol(G),
//                     M = diag(L) L^-1  -> ws (reuses Wnet_bf region)
//  K4b gs_apply:      out_i = w_i + sum_{j<i} M_ij w_j; row sets balanced
//                     {g, 31-g, 15-g, 16+g} -> uniform 47 loop iters/thread
// ---------------------------------------------------------------------------

typedef short s16x8 __attribute__((ext_vector_type(8)));
typedef float f32x4 __attribute__((ext_vector_type(4)));

#define GL_LDS16(gptr, lptr)                                                   \
    __builtin_amdgcn_global_load_lds(                                          \
        (const __attribute__((address_space(1))) void*)(gptr),                 \
        (__attribute__((address_space(3))) void*)(lptr), 16, 0, 0)

#define KP 1600   // padded K

// ========================= K3: 256x224 MFMA GEMM ===========================
// C[m][n] = (sum_k A[m][k]*B[n][k] + bias[n]) * 0.2
// A: [M][KP] bf16 row-major, B: [N][KP] bf16 row-major (pad cols zero).
// 512 threads = 8 waves; wave wv: wm = wv>>1 (64-row band), wn = wv&1
// (112-col half); per-wave output 64x112 (4x7 16x16 frags, acc 112 VGPR).
//
// Staging roles: waves 0-3 stage A (8 gloads: rows wv*64..+64), waves 4-7
// stage B (7 gloads: rows (wv-4)*56..+56). One __syncthreads per K64-tile
// drains vmcnt (stage->use distance = full tile >> HBM latency).
//
// LDS per buffer: A [256][64] bf16 (32 KB) + B [224][64] bf16 (28 KB).
// Swizzle (short units): phys = lin ^ ((row & 7) << 3); source col
// pre-swizzled (colE), ds_read applies the same XOR (per-lane constant).
__global__ __launch_bounds__(512, 1) void gemm_mfma_256(
    const __hip_bfloat16* __restrict__ A, const __hip_bfloat16* __restrict__ B,
    const float* __restrict__ bias, float* __restrict__ C,
    int M, int N, int K)
{
    __shared__ __align__(16) short lds[2][30720];   // 2 x 60 KB

    const int t = threadIdx.x;
    const int l = t & 63;
    const int wv = t >> 6;          // wave 0..7
    const int wm = wv >> 1;         // M-band 0..3 (64 rows)
    const int wn = wv & 1;          // N-half 0..1 (112 cols)

    // XCD-banded mapping: XCD (f&7) owns output row-band yb, sweeps all xb.
    const int f  = blockIdx.x;      // grid = 896 = 8 * 112
    const int xb = f >> 3;
    const int yb = f & 7;
    const int m0 = yb * 256;
    const int n0 = xb * 224;

    const short* As = (const short*)A;
    const short* Bs = (const short*)B;

    // ---- staging (per-lane source pre-swizzled; dst wave-uniform) ----
    const bool isA = wv < 4;
    const int colE = (((l & 7) ^ (l >> 3)) << 3);
    const size_t srcRow = isA ? (size_t)(m0 + wv * 64 + (l >> 3))
                              : (size_t)(n0 + (wv - 4) * 56 + (l >> 3));
    const size_t src0 = srcRow * KP + colE;
    const short* gsrc = isA ? As : Bs;
    const int dstBase = isA ? wv * 4096 : 16384 + (wv - 4) * 3584;

    // ---- fragment read constants (short units) ----
    const int sk0 = ((l >> 4) << 3) ^ ((l & 7) << 3);   // ks=0 swizzled col
    const int sk1 = sk0 ^ 32;                            // ks=1
    const int aoff = (wm * 64 + (l & 15)) * 64;                    // A region
    const int boff = 16384 + (wn * 112 + (l & 15)) * 64;           // B region

    f32x4 acc[4][7] = {};

#define STAGE_TILE(buf, T)                                                     \
    do {                                                                       \
        short* d_ = &lds[buf][dstBase];                                        \
        const short* s_ = gsrc + src0 + (size_t)(T) * 64;                      \
        GL_LDS16(s_ + (size_t)0 * 8 * KP, d_ + 0 * 512);                       \
        GL_LDS16(s_ + (size_t)1 * 8 * KP, d_ + 1 * 512);                       \
        GL_LDS16(s_ + (size_t)2 * 8 * KP, d_ + 2 * 512);                       \
        GL_LDS16(s_ + (size_t)3 * 8 * KP, d_ + 3 * 512);                       \
        GL_LDS16(s_ + (size_t)4 * 8 * KP, d_ + 4 * 512);                       \
        GL_LDS16(s_ + (size_t)5 * 8 * KP, d_ + 5 * 512);                       \
        GL_LDS16(s_ + (size_t)6 * 8 * KP, d_ + 6 * 512);                       \
        if (isA) GL_LDS16(s_ + (size_t)7 * 8 * KP, d_ + 7 * 512);              \
    } while (0)

    const int NT = K >> 6;          // 25
    STAGE_TILE(0, 0);
    __syncthreads();                // drains vmcnt(0): tile 0 ready

    for (int kt = 0; kt < NT; ++kt) {
        const int cur = kt & 1;
        const short* bufc = &lds[cur][0];

        // stage tile kt+1 into the other buffer (readers finished at the
        // __syncthreads ending tile kt-1; loads drain at this tile's end)
        if (kt + 1 < NT) STAGE_TILE(cur ^ 1, kt + 1);

        // ---- B fragments: all 14, held for the whole tile (56 VGPR) ----
        s16x8 bfr[7][2];
        #pragma unroll
        for (int ni = 0; ni < 7; ++ni) {
            bfr[ni][0] = *(const s16x8*)&bufc[boff + ni * 1024 + sk0];
            bfr[ni][1] = *(const s16x8*)&bufc[boff + ni * 1024 + sk1];
        }

        // ---- A per mi-row: read 2 frags, 14 MFMA ----
        #pragma unroll
        for (int mi = 0; mi < 4; ++mi) {
            s16x8 a0 = *(const s16x8*)&bufc[aoff + mi * 1024 + sk0];
            s16x8 a1 = *(const s16x8*)&bufc[aoff + mi * 1024 + sk1];
            __builtin_amdgcn_s_setprio(1);
            #pragma unroll
            for (int ni = 0; ni < 7; ++ni) {
                acc[mi][ni] = __builtin_amdgcn_mfma_f32_16x16x32_bf16(
                    a0, bfr[ni][0], acc[mi][ni], 0, 0, 0);
                acc[mi][ni] = __builtin_amdgcn_mfma_f32_16x16x32_bf16(
                    a1, bfr[ni][1], acc[mi][ni], 0, 0, 0);
            }
            __builtin_amdgcn_s_setprio(0);
        }

        // one barrier per K64-tile; also drains vmcnt(0) for tile kt+1's
        // stages (issued a full tile ago -> latency fully covered)
        __syncthreads();
    }
#undef STAGE_TILE

    // ---- epilogue: C/D layout col = lane&15, row = (lane>>4)*4 + reg ----
    const int row0 = m0 + wm * 64 + ((l >> 4) << 2);
    const int col0 = n0 + wn * 112 + (l & 15);
    #pragma unroll
    for (int ni = 0; ni < 7; ++ni) {
        const int n = col0 + ni * 16;
        const float bn = bias[n];
        #pragma unroll
        for (int mi = 0; mi < 4; ++mi) {
            const int r0 = row0 + mi * 16;
            #pragma unroll
            for (int r = 0; r < 4; ++r)
                C[(size_t)(r0 + r) * N + n] = (acc[mi][ni][r] + bn) * 0.2f;
        }
    }
}

// ==================== K0: W_net f32 -> bf16 (padded) =======================
__global__ __launch_bounds__(256) void wnet_to_bf16(
    const float* __restrict__ in, __hip_bfloat16* __restrict__ out)
{
    const size_t r = blockIdx.x;
    const int t = threadIdx.x;
    const float* src = in + r * 1568;
    __hip_bfloat16* dst = out + r * KP;

    for (int i = t; i < 392; i += 256) {        // 392 float4 = 1568
        float4 v = *(const float4*)(src + (i << 2));
        __hip_bfloat16 o[4] = {
            __float2bfloat16(v.x), __float2bfloat16(v.y),
            __float2bfloat16(v.z), __float2bfloat16(v.w)};
        *(ushort4*)&dst[i << 2] = *(const ushort4*)o;
    }
    if (t < 8)                                   // pad: 32 bf16 zeros
        *(ushort4*)&dst[1568 + (t << 2)] = make_ushort4(0, 0, 0, 0);
}

// ===================== K1: small fp32 GEMM (NT) ============================
#define TILE_M 64
#define TILE_N 64
#define TILE_K 16
#define LDS_STRIDE 72

__global__ __launch_bounds__(256) void gemm_nt_lp(
    const float* __restrict__ A, const float* __restrict__ B,
    const float* __restrict__ bias, __hip_bfloat16* __restrict__ C,
    int M, int N, int K, int ldc)
{
    __shared__ float As[TILE_K][LDS_STRIDE];
    __shared__ float Bsh[TILE_K][LDS_STRIDE];

    const int t  = threadIdx.x;
    const int tx = t & 15;
    const int ty = t >> 4;
    const int m0 = blockIdx.y * TILE_M;
    const int n0 = blockIdx.x * TILE_N;
    const int lrow = t >> 2;
    const int lk   = (t & 3) << 2;

    float acc[4][4] = {};

    for (int kt = 0; kt < K; kt += TILE_K) {
        float4 av = *(const float4*)(A + (size_t)(m0 + lrow) * K + kt + lk);
        float4 bv = make_float4(0.f, 0.f, 0.f, 0.f);
        if (n0 + lrow < N)
            bv = *(const float4*)(B + (size_t)(n0 + lrow) * K + kt + lk);

        __syncthreads();
        As[lk + 0][lrow] = av.x; As[lk + 1][lrow] = av.y;
        As[lk + 2][lrow] = av.z; As[lk + 3][lrow] = av.w;
        Bsh[lk + 0][lrow] = bv.x; Bsh[lk + 1][lrow] = bv.y;
        Bsh[lk + 2][lrow] = bv.z; Bsh[lk + 3][lrow] = bv.w;
        __syncthreads();

        #pragma unroll
        for (int k = 0; k < TILE_K; ++k) {
            float4 a = *(const float4*)&As[k][ty << 2];
            float4 b = *(const float4*)&Bsh[k][tx << 2];
            acc[0][0] += a.x * b.x; acc[0][1] += a.x * b.y;
            acc[0][2] += a.x * b.z; acc[0][3] += a.x * b.w;
            acc[1][0] += a.y * b.x; acc[1][1] += a.y * b.y;
            acc[1][2] += a.y * b.z; acc[1][3] += a.y * b.w;
            acc[2][0] += a.z * b.x; acc[2][1] += a.z * b.y;
            acc[2][2] += a.z * b.z; acc[2][3] += a.z * b.w;
            acc[3][0] += a.w * b.x; acc[3][1] += a.w * b.y;
            acc[3][2] += a.w * b.z; acc[3][3] += a.w * b.w;
        }
    }

    #pragma unroll
    for (int j = 0; j < 4; ++j) {
        int n = n0 + (tx << 2) + j;
        if (n < N) {
            float bn = bias[n];
            #pragma unroll
            for (int i = 0; i < 4; ++i) {
                float v = (acc[i][j] + bn - 0.5f) / 0.2f;
                C[(size_t)(m0 + (ty << 2) + i) * ldc + n] = __float2bfloat16(v);
            }
        }
    }
}

// ===================== K2: restored half, bf16 (padded) ====================
__global__ __launch_bounds__(256) void build_restored(
    const float* __restrict__ xr, __hip_bfloat16* __restrict__ x)
{
    const int b = blockIdx.x;
    const int t = threadIdx.x;
    if (t < 196) {
        float4 v = *(const float4*)(xr + (size_t)b * 784 + (t << 2));
        __hip_bfloat16 o[4] = {
            __float2bfloat16((v.x - 0.5f) / 0.2f),
            __float2bfloat16((v.y - 0.5f) / 0.2f),
            __float2bfloat16((v.z - 0.5f) / 0.2f),
            __float2bfloat16((v.w - 0.5f) / 0.2f)};
        *(ushort4*)&x[(size_t)b * KP + 784 + (t << 2)] = *(const ushort4*)o;
    } else if (t < 204) {                        // pad cols 1568..1599
        *(ushort4*)&x[(size_t)b * KP + 1568 + ((t - 196) << 2)] =
            make_ushort4(0, 0, 0, 0);
    }
}

// ==================== K4a: Gram + Cholesky solve ===========================
#define GS_N 32
#define GS_D 784

__global__ __launch_bounds__(256, 4) void gram_solve(
    const float* __restrict__ out, float* __restrict__ Mws)
{
    __shared__ __align__(16) short Wc[GS_N * 64];   // 4 KB, XOR-swizzled
    __shared__ float Gs[GS_N][GS_N + 1];            // 4224 B (G -> L)
    __shared__ float Ms[GS_N][GS_N + 1];            // 4224 B
    __shared__ float Ld[GS_N];

    const int t = threadIdx.x;
    const int l = t & 63;
    const int w = t >> 6;
    const float* row0 = out + (size_t)blockIdx.x * (GS_N * GS_D);

    const int wr = w >> 1, wc2 = w & 1;
    const int ra = wr * 16 + (l & 15);
    const int rb = wc2 * 16 + (l & 15);
    const int kg = l >> 4;

    f32x4 acc = {};

    for (int k0 = 0; k0 < 832; k0 += 64) {   // 13 chunks, k >= 784 zero-pad
        #pragma unroll
        for (int hh = 0; hh < 2; ++hh) {
            const int h   = t + hh * 256;    // 0..511 = 32 rows x 16 qgrans
            const int r   = h >> 4;
            const int hg  = h & 15;          // quarter-granule (4 elems)
            const int col = k0 + (hg << 2);
            ushort4 u = make_ushort4(0, 0, 0, 0);
            if (col < GS_D) {
                float4 v = *(const float4*)(row0 + r * GS_D + col);
                __hip_bfloat16 hb[4] = {
                    __float2bfloat16(v.x), __float2bfloat16(v.y),
                    __float2bfloat16(v.z), __float2bfloat16(v.w)};
                u = *(const ushort4*)hb;
            }
            const int gp = (hg >> 1) ^ (r & 7);   // 16B-granule swizzle
            *(ushort4*)&Wc[(r << 6) + (gp << 3) + ((hg & 1) << 2)] = u;
        }
        __syncthreads();

        #pragma unroll
        for (int s = 0; s < 2; ++s) {
            const int ga = ((s << 2) + kg) ^ (ra & 7);
            const int gb = ((s << 2) + kg) ^ (rb & 7);
            s16x8 af = *(const s16x8*)&Wc[(ra << 6) + (ga << 3)];
            s16x8 bf = *(const s16x8*)&Wc[(rb << 6) + (gb << 3)];
            acc = __builtin_amdgcn_mfma_f32_16x16x32_bf16(af, bf, acc, 0, 0, 0);
        }
        __syncthreads();
    }

    {
        const int di = wr * 16 + (l >> 4) * 4;
        const int dj = wc2 * 16 + (l & 15);
        #pragma unroll
        for (int r = 0; r < 4; ++r) Gs[di + r][dj] = acc[r];
    }
    for (int z = t; z < GS_N * (GS_N + 1); z += 256) ((float*)Ms)[z] = 0.f;
    __syncthreads();

    // Cholesky, lower triangle in place (diag in Ld)
    for (int k = 0; k < GS_N; ++k) {
        const float sk = sqrtf(Gs[k][k]);
        if (t == k) Ld[k] = sk;
        if (t > k && t < GS_N) Gs[t][k] /= sk;
        __syncthreads();
        if (t > k && t < GS_N) {
            const float lik = Gs[t][k];
            for (int j = k + 1; j <= t; ++j)
                Gs[t][j] -= lik * Gs[j][k];
        }
        __syncthreads();
    }

    // M = diag(L) * L^-1, column-parallel forward substitution
    if (t < GS_N) {
        const int j = t;
        Ms[j][j] = 1.0f / Ld[j];
        for (int i = j + 1; i < GS_N; ++i) {
            float a = 0.f;
            for (int k = j; k < i; ++k)
                a += Gs[i][k] * Ms[k][j];
            Ms[i][j] = -a / Ld[i];
        }
        for (int i = j + 1; i < GS_N; ++i)
            Ms[i][j] *= Ld[i];
    }
    __syncthreads();

    {
        const int i = t >> 3, j0 = (t & 7) << 2;
        float4 mv = make_float4(Ms[i][j0], Ms[i][j0 + 1],
                                Ms[i][j0 + 2], Ms[i][j0 + 3]);
        *(float4*)(Mws + (size_t)blockIdx.x * 1024 + (t << 2)) = mv;
    }
}

// ======================= K4b: apply correction =============================
// Balanced rows per thread-group g = t>>5: {g, 31-g, 15-g, 16+g}; two shared
// j-loops of lengths (31-g) and (16+g) -> uniform 47 iters for every thread.
__global__ __launch_bounds__(256, 8) void gs_apply(
    float* __restrict__ out, const float* __restrict__ Mws)
{
    __shared__ float4 Wf[GS_N][28];     // 14336 B (f32 chunk)
    __shared__ float  Ml[GS_N][36];     // 4608 B (padded for f4 writes)

    const int t = threadIdx.x;
    const int b = blockIdx.y;
    const int k0 = blockIdx.x * 112;
    float* row0 = out + (size_t)b * (GS_N * GS_D);

    {
        float4 mv = *(const float4*)(Mws + (size_t)b * 1024 + (t << 2));
        const int i = t >> 3, j0 = (t & 7) << 2;
        *(float4*)&Ml[i][j0] = mv;
    }
    #pragma unroll
    for (int hh = 0; hh < 4; ++hh) {
        const int h = t + hh * 256;     // 0..1023
        const int r = h >> 5, c = h & 31;
        if (c < 28)
            Wf[r][c] = *(const float4*)(row0 + r * GS_D + k0 + (c << 2));
    }
    __syncthreads();

    const int g  = t >> 5;              // 0..7
    const int c4 = t & 31;              // float4 column
    if (c4 < 28) {
        const int rA = g, rB = 31 - g, rC = 15 - g, rD = 16 + g;
        float4 vA = Wf[rA][c4];
        float4 vB = Wf[rB][c4];
        float4 vC = Wf[rC][c4];
        float4 vD = Wf[rD][c4];
        // loop 1: rows rB (full) and rA (j < rA), length 31-g
        for (int j = 0; j < rB; ++j) {
            const float4 wj = Wf[j][c4];
            const float mA = (j < rA) ? Ml[rA][j] : 0.f;
            const float mB = Ml[rB][j];
            vA.x += mA * wj.x; vA.y += mA * wj.y;
            vA.z += mA * wj.z; vA.w += mA * wj.w;
            vB.x += mB * wj.x; vB.y += mB * wj.y;
            vB.z += mB * wj.z; vB.w += mB * wj.w;
        }
        // loop 2: rows rD (full) and rC (j < rC), length 16+g
        for (int j = 0; j < rD; ++j) {
            const float4 wj = Wf[j][c4];
            const float mC = (j < rC) ? Ml[rC][j] : 0.f;
            const float mD = Ml[rD][j];
            vC.x += mC * wj.x; vC.y += mC * wj.y;
            vC.z += mC * wj.z; vC.w += mC * wj.w;
            vD.x += mD * wj.x; vD.y += mD * wj.y;
            vD.z += mD * wj.z; vD.w += mD * wj.w;
        }
        *(float4*)(row0 + rA * GS_D + k0 + (c4 << 2)) = vA;
        *(float4*)(row0 + rB * GS_D + k0 + (c4 << 2)) = vB;
        *(float4*)(row0 + rC * GS_D + k0 + (c4 << 2)) = vC;
        *(float4*)(row0 + rD * GS_D + k0 + (c4 << 2)) = vD;
    }
}

// ================================ launch ===================================
extern "C" void kernel_launch(void* const* d_in, const int* in_sizes, int n_in,
                              void* d_out, int out_size, void* d_ws, size_t ws_size,
                              hipStream_t stream)
{
    const float* xd   = (const float*)d_in[0];  // [2048, 832]
    const float* xr   = (const float*)d_in[1];  // [2048, 1, 28, 28]
    const float* Wlp  = (const float*)d_in[2];  // [784, 832]
    const float* blp  = (const float*)d_in[3];  // [784]
    const float* Wnet = (const float*)d_in[4];  // [25088, 1568]
    const float* bnet = (const float*)d_in[5];  // [25088]
    float* out = (float*)d_out;                 // [2048, 32, 784] f32

    const int B = 2048, IN_LP = 832, IMG = 784, OUT = 32 * 784;

    // workspace: [Wnet_bf: 25088*1600*2 = 80.28 MB][x_bf: 2048*1600*2 = 6.55 MB]
    __hip_bfloat16* Wnet_bf = (__hip_bfloat16*)d_ws;
    __hip_bfloat16* x_bf =
        (__hip_bfloat16*)((char*)d_ws + (size_t)OUT * KP * 2);
    // M workspace overlays Wnet_bf region (free after K3; stream-ordered).
    float* Mws = (float*)d_ws;                  // [2048][32][32] f32 = 8.4 MB

    // K0: W_net fp32 -> bf16, padded to KP
    wnet_to_bf16<<<OUT, 256, 0, stream>>>(Wnet, Wnet_bf);

    // K1: linear projection + normalize -> bf16 x[:, :784] (ld = KP)
    gemm_nt_lp<<<dim3((IMG + TILE_N - 1) / TILE_N, B / TILE_M), 256, 0, stream>>>(
        xd, Wlp, blp, x_bf, B, IMG, IN_LP, KP);

    // K2: normalized restored image -> bf16 x[:, 784:1568]; pad zeros
    build_restored<<<B, 256, 0, stream>>>(xr, x_bf);

    // K3: big MFMA GEMM -> d_out (fp32); grid 896 = 8 XCD bands x 112 panels
    gemm_mfma_256<<<dim3(896), 512, 0, stream>>>(
        x_bf, Wnet_bf, bnet, out, B, OUT, KP);

    // K4a: per-batch Gram + Cholesky -> M
    gram_solve<<<B, 256, 0, stream>>>(out, Mws);

    // K4b: apply rank-32 correction in place (balanced row sets)
    gs_apply<<<dim3(7, B), 256, 0, stream>>>(out, Mws);
}

// Round 8
// 441.539 us; speedup vs baseline: 1.0563x; 1.0150x over previous
//
#include <hip/hip_runtime.h>
#include <hip/hip_bf16.h>
#include <stdint.h>

// ---------------------------------------------------------------------------
// Pipeline (K padded 1568 -> 1600 so BK=64 divides; pad cols are zeros):
//  KP prep012 (merged):
//    - K1 part: ws.x_bf[:, :784] = bf16((xd@W_lp^T + b_lp - .5)/.2)
//    - K2 part: ws.x_bf[:, 784:1568] = bf16((xr - .5)/.2); pad = 0
//    - K0 part: ws.Wnet_bf[r][0:1568] = bf16(W_net[r]); [1568:1600]=0
//  K3 gemm_mfma_256:  d_out = (x_bf @ Wnet_bf^T + b_net)*0.2   [2048,25088] f32
//                     256x224 tile (grid 896 = 3.5*256), BK=64, 8 waves,
//                     2-buffer LDS, ONE __syncthreads per K64-tile,
//                     XOR-swizzled LDS (0 conflicts), XCD bands.
//  K4a gram_solve:    per batch: G = W W^T via REGISTER-DIRECT MFMA (global
//                     f32 -> cvt -> mfma, no LDS staging, no barriers),
//                     L = chol(G), M = diag(L) L^-1 -> ws
//  K4b gs_apply:      out_i = w_i + sum_{j<i} M_ij w_j; balanced row sets
// ---------------------------------------------------------------------------

typedef short s16x8 __attribute__((ext_vector_type(8)));
typedef float f32x4 __attribute__((ext_vector_type(4)));

#define GL_LDS16(gptr, lptr)                                                   \
    __builtin_amdgcn_global_load_lds(                                          \
        (const __attribute__((address_space(1))) void*)(gptr),                 \
        (__attribute__((address_space(3))) void*)(lptr), 16, 0, 0)

#define KP 1600   // padded K

// ========================= K3: 256x224 MFMA GEMM ===========================
// (unchanged from round 7 — see comments there)
__global__ __launch_bounds__(512, 1) void gemm_mfma_256(
    const __hip_bfloat16* __restrict__ A, const __hip_bfloat16* __restrict__ B,
    const float* __restrict__ bias, float* __restrict__ C,
    int M, int N, int K)
{
    __shared__ __align__(16) short lds[2][30720];   // 2 x 60 KB

    const int t = threadIdx.x;
    const int l = t & 63;
    const int wv = t >> 6;          // wave 0..7
    const int wm = wv >> 1;         // M-band 0..3 (64 rows)
    const int wn = wv & 1;          // N-half 0..1 (112 cols)

    const int f  = blockIdx.x;      // grid = 896 = 8 * 112
    const int xb = f >> 3;
    const int yb = f & 7;
    const int m0 = yb * 256;
    const int n0 = xb * 224;

    const short* As = (const short*)A;
    const short* Bs = (const short*)B;

    const bool isA = wv < 4;
    const int colE = (((l & 7) ^ (l >> 3)) << 3);
    const size_t srcRow = isA ? (size_t)(m0 + wv * 64 + (l >> 3))
                              : (size_t)(n0 + (wv - 4) * 56 + (l >> 3));
    const size_t src0 = srcRow * KP + colE;
    const short* gsrc = isA ? As : Bs;
    const int dstBase = isA ? wv * 4096 : 16384 + (wv - 4) * 3584;

    const int sk0 = ((l >> 4) << 3) ^ ((l & 7) << 3);   // ks=0 swizzled col
    const int sk1 = sk0 ^ 32;                            // ks=1
    const int aoff = (wm * 64 + (l & 15)) * 64;
    const int boff = 16384 + (wn * 112 + (l & 15)) * 64;

    f32x4 acc[4][7] = {};

#define STAGE_TILE(buf, T)                                                     \
    do {                                                                       \
        short* d_ = &lds[buf][dstBase];                                        \
        const short* s_ = gsrc + src0 + (size_t)(T) * 64;                      \
        GL_LDS16(s_ + (size_t)0 * 8 * KP, d_ + 0 * 512);                       \
        GL_LDS16(s_ + (size_t)1 * 8 * KP, d_ + 1 * 512);                       \
        GL_LDS16(s_ + (size_t)2 * 8 * KP, d_ + 2 * 512);                       \
        GL_LDS16(s_ + (size_t)3 * 8 * KP, d_ + 3 * 512);                       \
        GL_LDS16(s_ + (size_t)4 * 8 * KP, d_ + 4 * 512);                       \
        GL_LDS16(s_ + (size_t)5 * 8 * KP, d_ + 5 * 512);                       \
        GL_LDS16(s_ + (size_t)6 * 8 * KP, d_ + 6 * 512);                       \
        if (isA) GL_LDS16(s_ + (size_t)7 * 8 * KP, d_ + 7 * 512);              \
    } while (0)

    const int NT = K >> 6;          // 25
    STAGE_TILE(0, 0);
    __syncthreads();                // drains vmcnt(0): tile 0 ready

    for (int kt = 0; kt < NT; ++kt) {
        const int cur = kt & 1;
        const short* bufc = &lds[cur][0];

        if (kt + 1 < NT) STAGE_TILE(cur ^ 1, kt + 1);

        s16x8 bfr[7][2];
        #pragma unroll
        for (int ni = 0; ni < 7; ++ni) {
            bfr[ni][0] = *(const s16x8*)&bufc[boff + ni * 1024 + sk0];
            bfr[ni][1] = *(const s16x8*)&bufc[boff + ni * 1024 + sk1];
        }

        #pragma unroll
        for (int mi = 0; mi < 4; ++mi) {
            s16x8 a0 = *(const s16x8*)&bufc[aoff + mi * 1024 + sk0];
            s16x8 a1 = *(const s16x8*)&bufc[aoff + mi * 1024 + sk1];
            __builtin_amdgcn_s_setprio(1);
            #pragma unroll
            for (int ni = 0; ni < 7; ++ni) {
                acc[mi][ni] = __builtin_amdgcn_mfma_f32_16x16x32_bf16(
                    a0, bfr[ni][0], acc[mi][ni], 0, 0, 0);
                acc[mi][ni] = __builtin_amdgcn_mfma_f32_16x16x32_bf16(
                    a1, bfr[ni][1], acc[mi][ni], 0, 0, 0);
            }
            __builtin_amdgcn_s_setprio(0);
        }

        __syncthreads();
    }
#undef STAGE_TILE

    const int row0 = m0 + wm * 64 + ((l >> 4) << 2);
    const int col0 = n0 + wn * 112 + (l & 15);
    #pragma unroll
    for (int ni = 0; ni < 7; ++ni) {
        const int n = col0 + ni * 16;
        const float bn = bias[n];
        #pragma unroll
        for (int mi = 0; mi < 4; ++mi) {
            const int r0 = row0 + mi * 16;
            #pragma unroll
            for (int r = 0; r < 4; ++r)
                C[(size_t)(r0 + r) * N + n] = (acc[mi][ni][r] + bn) * 0.2f;
        }
    }
}

// ================= prep012: merged K1 + K2 + K0 ============================
#define TILE_M 64
#define TILE_N 64
#define TILE_K 16
#define LDS_STRIDE 72
#define NB_K1 416        // 13 x 32 tiles
#define NB_K2 2048
#define NB_K0 25088

__global__ __launch_bounds__(256) void prep012(
    const float* __restrict__ xd, const float* __restrict__ xr,
    const float* __restrict__ Wlp, const float* __restrict__ blp,
    const float* __restrict__ Wnet,
    __hip_bfloat16* __restrict__ Wnet_bf, __hip_bfloat16* __restrict__ x_bf)
{
    const int bid = blockIdx.x;
    const int t = threadIdx.x;

    if (bid < NB_K1) {
        // ---- K1: x_bf[:, :784] = bf16((xd @ Wlp^T + blp - .5)/.2) ----
        __shared__ float As[TILE_K][LDS_STRIDE];
        __shared__ float Bsh[TILE_K][LDS_STRIDE];

        const int bx = bid % 13, by = bid / 13;
        const int tx = t & 15;
        const int ty = t >> 4;
        const int m0 = by * TILE_M;
        const int n0 = bx * TILE_N;
        const int lrow = t >> 2;
        const int lk   = (t & 3) << 2;
        const int Kd = 832, Nd = 784;

        float acc[4][4] = {};

        for (int kt = 0; kt < Kd; kt += TILE_K) {
            float4 av = *(const float4*)(xd + (size_t)(m0 + lrow) * Kd + kt + lk);
            float4 bv = make_float4(0.f, 0.f, 0.f, 0.f);
            if (n0 + lrow < Nd)
                bv = *(const float4*)(Wlp + (size_t)(n0 + lrow) * Kd + kt + lk);

            __syncthreads();
            As[lk + 0][lrow] = av.x; As[lk + 1][lrow] = av.y;
            As[lk + 2][lrow] = av.z; As[lk + 3][lrow] = av.w;
            Bsh[lk + 0][lrow] = bv.x; Bsh[lk + 1][lrow] = bv.y;
            Bsh[lk + 2][lrow] = bv.z; Bsh[lk + 3][lrow] = bv.w;
            __syncthreads();

            #pragma unroll
            for (int k = 0; k < TILE_K; ++k) {
                float4 a = *(const float4*)&As[k][ty << 2];
                float4 b = *(const float4*)&Bsh[k][tx << 2];
                acc[0][0] += a.x * b.x; acc[0][1] += a.x * b.y;
                acc[0][2] += a.x * b.z; acc[0][3] += a.x * b.w;
                acc[1][0] += a.y * b.x; acc[1][1] += a.y * b.y;
                acc[1][2] += a.y * b.z; acc[1][3] += a.y * b.w;
                acc[2][0] += a.z * b.x; acc[2][1] += a.z * b.y;
                acc[2][2] += a.z * b.z; acc[2][3] += a.z * b.w;
                acc[3][0] += a.w * b.x; acc[3][1] += a.w * b.y;
                acc[3][2] += a.w * b.z; acc[3][3] += a.w * b.w;
            }
        }

        #pragma unroll
        for (int j = 0; j < 4; ++j) {
            int n = n0 + (tx << 2) + j;
            if (n < Nd) {
                float bn = blp[n];
                #pragma unroll
                for (int i = 0; i < 4; ++i) {
                    float v = (acc[i][j] + bn - 0.5f) / 0.2f;
                    x_bf[(size_t)(m0 + (ty << 2) + i) * KP + n] =
                        __float2bfloat16(v);
                }
            }
        }
    } else if (bid < NB_K1 + NB_K2) {
        // ---- K2: x_bf[:, 784:1568] = bf16((xr - .5)/.2); pad zeros ----
        const int b = bid - NB_K1;
        if (t < 196) {
            float4 v = *(const float4*)(xr + (size_t)b * 784 + (t << 2));
            __hip_bfloat16 o[4] = {
                __float2bfloat16((v.x - 0.5f) / 0.2f),
                __float2bfloat16((v.y - 0.5f) / 0.2f),
                __float2bfloat16((v.z - 0.5f) / 0.2f),
                __float2bfloat16((v.w - 0.5f) / 0.2f)};
            *(ushort4*)&x_bf[(size_t)b * KP + 784 + (t << 2)] =
                *(const ushort4*)o;
        } else if (t < 204) {
            *(ushort4*)&x_bf[(size_t)b * KP + 1568 + ((t - 196) << 2)] =
                make_ushort4(0, 0, 0, 0);
        }
    } else {
        // ---- K0: Wnet_bf[r][0:1568] = bf16(Wnet[r]); pad zeros ----
        const size_t r = bid - (NB_K1 + NB_K2);
        const float* src = Wnet + r * 1568;
        __hip_bfloat16* dst = Wnet_bf + r * KP;

        for (int i = t; i < 392; i += 256) {
            float4 v = *(const float4*)(src + (i << 2));
            __hip_bfloat16 o[4] = {
                __float2bfloat16(v.x), __float2bfloat16(v.y),
                __float2bfloat16(v.z), __float2bfloat16(v.w)};
            *(ushort4*)&dst[i << 2] = *(const ushort4*)o;
        }
        if (t < 8)
            *(ushort4*)&dst[1568 + (t << 2)] = make_ushort4(0, 0, 0, 0);
    }
}

// ==================== K4a: Gram + Cholesky solve ===========================
// Gram via register-direct MFMA: each wave computes one 16x16 quadrant of
// G = W W^T reading f32 fragments straight from global (L2-resident: 100 KB
// per block), converting to bf16 in-reg. No LDS staging, no barriers in the
// Gram loop. Then Cholesky + forward substitution as before.
#define GS_N 32
#define GS_D 784

__device__ __forceinline__ s16x8 cvt8(float4 a, float4 b) {
    __hip_bfloat16 h[8] = {
        __float2bfloat16(a.x), __float2bfloat16(a.y),
        __float2bfloat16(a.z), __float2bfloat16(a.w),
        __float2bfloat16(b.x), __float2bfloat16(b.y),
        __float2bfloat16(b.z), __float2bfloat16(b.w)};
    return *(const s16x8*)h;
}

__global__ __launch_bounds__(256, 4) void gram_solve(
    const float* __restrict__ out, float* __restrict__ Mws)
{
    __shared__ float Gs[GS_N][GS_N + 1];            // 4224 B (G -> L)
    __shared__ float Ms[GS_N][GS_N + 1];            // 4224 B
    __shared__ float Ld[GS_N];

    const int t = threadIdx.x;
    const int l = t & 63;
    const int w = t >> 6;
    const float* row0 = out + (size_t)blockIdx.x * (GS_N * GS_D);

    const int wr = w >> 1, wc2 = w & 1;
    const int ra = wr * 16 + (l & 15);   // Gram row index (A operand)
    const int rb = wc2 * 16 + (l & 15);  // Gram col index (B operand)
    const int kg = l >> 4;               // k-subgroup 0..3

    const float* pa = row0 + (size_t)ra * GS_D + kg * 8;
    const float* pb = row0 + (size_t)rb * GS_D + kg * 8;

    f32x4 acc = {};
    #pragma unroll 2
    for (int s = 0; s < 24; ++s) {       // 24 full K32 steps (768 cols)
        float4 a0 = *(const float4*)(pa + s * 32);
        float4 a1 = *(const float4*)(pa + s * 32 + 4);
        float4 b0 = *(const float4*)(pb + s * 32);
        float4 b1 = *(const float4*)(pb + s * 32 + 4);
        acc = __builtin_amdgcn_mfma_f32_16x16x32_bf16(
            cvt8(a0, a1), cvt8(b0, b1), acc, 0, 0, 0);
    }
    {                                    // tail cols 768..783: kg 0,1 valid
        s16x8 af = {}, bf = {};
        if (kg < 2) {
            float4 a0 = *(const float4*)(pa + 768);
            float4 a1 = *(const float4*)(pa + 768 + 4);
            float4 b0 = *(const float4*)(pb + 768);
            float4 b1 = *(const float4*)(pb + 768 + 4);
            af = cvt8(a0, a1); bf = cvt8(b0, b1);
        }
        acc = __builtin_amdgcn_mfma_f32_16x16x32_bf16(af, bf, acc, 0, 0, 0);
    }

    // C/D layout: col = lane&15, row = (lane>>4)*4 + reg
    {
        const int di = wr * 16 + (l >> 4) * 4;
        const int dj = wc2 * 16 + (l & 15);
        #pragma unroll
        for (int r = 0; r < 4; ++r) Gs[di + r][dj] = acc[r];
    }
    for (int z = t; z < GS_N * (GS_N + 1); z += 256) ((float*)Ms)[z] = 0.f;
    __syncthreads();

    // Cholesky, lower triangle in place (diag in Ld)
    for (int k = 0; k < GS_N; ++k) {
        const float sk = sqrtf(Gs[k][k]);
        if (t == k) Ld[k] = sk;
        if (t > k && t < GS_N) Gs[t][k] /= sk;
        __syncthreads();
        if (t > k && t < GS_N) {
            const float lik = Gs[t][k];
            for (int j = k + 1; j <= t; ++j)
                Gs[t][j] -= lik * Gs[j][k];
        }
        __syncthreads();
    }

    // M = diag(L) * L^-1, column-parallel forward substitution
    if (t < GS_N) {
        const int j = t;
        Ms[j][j] = 1.0f / Ld[j];
        for (int i = j + 1; i < GS_N; ++i) {
            float a = 0.f;
            for (int k = j; k < i; ++k)
                a += Gs[i][k] * Ms[k][j];
            Ms[i][j] = -a / Ld[i];
        }
        for (int i = j + 1; i < GS_N; ++i)
            Ms[i][j] *= Ld[i];
    }
    __syncthreads();

    {
        const int i = t >> 3, j0 = (t & 7) << 2;
        float4 mv = make_float4(Ms[i][j0], Ms[i][j0 + 1],
                                Ms[i][j0 + 2], Ms[i][j0 + 3]);
        *(float4*)(Mws + (size_t)blockIdx.x * 1024 + (t << 2)) = mv;
    }
}

// ======================= K4b: apply correction =============================
// Balanced rows per thread-group g = t>>5: {g, 31-g, 15-g, 16+g}; two shared
// j-loops of lengths (31-g) and (16+g) -> uniform 47 iters for every thread.
__global__ __launch_bounds__(256, 8) void gs_apply(
    float* __restrict__ out, const float* __restrict__ Mws)
{
    __shared__ float4 Wf[GS_N][28];     // 14336 B (f32 chunk)
    __shared__ float  Ml[GS_N][36];     // 4608 B (padded for f4 writes)

    const int t = threadIdx.x;
    const int b = blockIdx.y;
    const int k0 = blockIdx.x * 112;
    float* row0 = out + (size_t)b * (GS_N * GS_D);

    {
        float4 mv = *(const float4*)(Mws + (size_t)b * 1024 + (t << 2));
        const int i = t >> 3, j0 = (t & 7) << 2;
        *(float4*)&Ml[i][j0] = mv;
    }
    #pragma unroll
    for (int hh = 0; hh < 4; ++hh) {
        const int h = t + hh * 256;     // 0..1023
        const int r = h >> 5, c = h & 31;
        if (c < 28)
            Wf[r][c] = *(const float4*)(row0 + r * GS_D + k0 + (c << 2));
    }
    __syncthreads();

    const int g  = t >> 5;              // 0..7
    const int c4 = t & 31;              // float4 column
    if (c4 < 28) {
        const int rA = g, rB = 31 - g, rC = 15 - g, rD = 16 + g;
        float4 vA = Wf[rA][c4];
        float4 vB = Wf[rB][c4];
        float4 vC = Wf[rC][c4];
        float4 vD = Wf[rD][c4];
        for (int j = 0; j < rB; ++j) {
            const float4 wj = Wf[j][c4];
            const float mA = (j < rA) ? Ml[rA][j] : 0.f;
            const float mB = Ml[rB][j];
            vA.x += mA * wj.x; vA.y += mA * wj.y;
            vA.z += mA * wj.z; vA.w += mA * wj.w;
            vB.x += mB * wj.x; vB.y += mB * wj.y;
            vB.z += mB * wj.z; vB.w += mB * wj.w;
        }
        for (int j = 0; j < rD; ++j) {
            const float4 wj = Wf[j][c4];
            const float mC = (j < rC) ? Ml[rC][j] : 0.f;
            const float mD = Ml[rD][j];
            vC.x += mC * wj.x; vC.y += mC * wj.y;
            vC.z += mC * wj.z; vC.w += mC * wj.w;
            vD.x += mD * wj.x; vD.y += mD * wj.y;
            vD.z += mD * wj.z; vD.w += mD * wj.w;
        }
        *(float4*)(row0 + rA * GS_D + k0 + (c4 << 2)) = vA;
        *(float4*)(row0 + rB * GS_D + k0 + (c4 << 2)) = vB;
        *(float4*)(row0 + rC * GS_D + k0 + (c4 << 2)) = vC;
        *(float4*)(row0 + rD * GS_D + k0 + (c4 << 2)) = vD;
    }
}

// ================================ launch ===================================
extern "C" void kernel_launch(void* const* d_in, const int* in_sizes, int n_in,
                              void* d_out, int out_size, void* d_ws, size_t ws_size,
                              hipStream_t stream)
{
    const float* xd   = (const float*)d_in[0];  // [2048, 832]
    const float* xr   = (const float*)d_in[1];  // [2048, 1, 28, 28]
    const float* Wlp  = (const float*)d_in[2];  // [784, 832]
    const float* blp  = (const float*)d_in[3];  // [784]
    const float* Wnet = (const float*)d_in[4];  // [25088, 1568]
    const float* bnet = (const float*)d_in[5];  // [25088]
    float* out = (float*)d_out;                 // [2048, 32, 784] f32

    const int B = 2048, OUT = 32 * 784;

    // workspace: [Wnet_bf: 25088*1600*2 = 80.28 MB][x_bf: 2048*1600*2 = 6.55 MB]
    __hip_bfloat16* Wnet_bf = (__hip_bfloat16*)d_ws;
    __hip_bfloat16* x_bf =
        (__hip_bfloat16*)((char*)d_ws + (size_t)OUT * KP * 2);
    // M workspace overlays Wnet_bf region (free after K3; stream-ordered).
    float* Mws = (float*)d_ws;                  // [2048][32][32] f32 = 8.4 MB

    // prep: merged K1 (tiles first) + K2 + K0
    prep012<<<NB_K1 + NB_K2 + NB_K0, 256, 0, stream>>>(
        xd, xr, Wlp, blp, Wnet, Wnet_bf, x_bf);

    // K3: big MFMA GEMM -> d_out (fp32); grid 896 = 8 XCD bands x 112 panels
    gemm_mfma_256<<<dim3(896), 512, 0, stream>>>(
        x_bf, Wnet_bf, bnet, out, B, OUT, KP);

    // K4a: per-batch Gram (register-direct) + Cholesky -> M
    gram_solve<<<B, 256, 0, stream>>>(out, Mws);

    // K4b: apply rank-32 correction in place (balanced row sets)
    gs_apply<<<dim3(7, B), 256, 0, stream>>>(out, Mws);
}